// Round 2
// baseline (2585.167 us; speedup 1.0000x reference)
//
#include <hip/hip_runtime.h>
#include <hip/hip_bf16.h>

typedef __hip_bfloat16 bf16;

#define IN_C 128

template <typename TOUT> __device__ inline TOUT f2o(float v);
template <> __device__ inline float f2o<float>(float v) { return v; }
template <> __device__ inline bf16 f2o<bf16>(float v) { return __float2bfloat16(v); }

// ---- dtype detection: flag=1 if buffer is bf16, 0 if float32 ----
// For a bf16 buffer, even-index u16 halves are bf16 values of N(0,1) draws ->
// biased exponents (~[100,150]). For f32, even-index halves are mantissa bits
// -> uniform exponents. Count "sane" exponents over 4096 samples.
__global__ __launch_bounds__(256) void detect_k(const unsigned short* __restrict__ xb,
                                                int* __restrict__ flag) {
  __shared__ int s_sane;
  if (threadIdx.x == 0) s_sane = 0;
  __syncthreads();
  int sane = 0;
  for (int i = threadIdx.x; i < 4096; i += 256) {
    unsigned short h = xb[2 * i];
    int e = (h >> 7) & 0xFF;
    if (e >= 100 && e <= 150) sane++;
  }
  atomicAdd(&s_sane, sane);
  __syncthreads();
  if (threadIdx.x == 0) *flag = (s_sane > 3072) ? 1 : 0;
}

// elementwise convert (branch on runtime flag) into f32 workspace
__global__ __launch_bounds__(256) void cvt_k(const void* __restrict__ in,
                                             float* __restrict__ out, int n,
                                             const int* __restrict__ flag) {
  int i = blockIdx.x * 256 + threadIdx.x;
  if (i >= n) return;
  if (*flag) out[i] = __bfloat162float(((const bf16*)in)[i]);
  else       out[i] = ((const float*)in)[i];
}

// final output write (branch on runtime flag)
__global__ __launch_bounds__(256) void out_k(const float* __restrict__ src,
                                             void* __restrict__ out, int n,
                                             const int* __restrict__ flag) {
  int i = blockIdx.x * 256 + threadIdx.x;
  if (i >= n) return;
  float v = src[i];
  if (*flag) ((bf16*)out)[i] = __float2bfloat16(v);
  else       ((float*)out)[i] = v;
}

// out[n, C] = act( (x[n,K] + preb) @ W[K,C] + postb )   (all f32)
// ACT: 0=none, 1=leaky_relu(0.01), 2=relu
template <int K, int C, int ACT, bool PREB, bool POSTB>
__global__ __launch_bounds__(256) void lin_k(const float* __restrict__ x,
                                             const float* __restrict__ W,
                                             const float* __restrict__ preb,
                                             const float* __restrict__ postb,
                                             float* __restrict__ out, int n) {
  constexpr int G = 256 / C;   // row groups per block
  constexpr int R = 8;         // rows per group
  constexpr int RPB = G * R;   // rows per block
  __shared__ float xs[RPB * K];
  const int tid = threadIdx.x;
  const int row0 = blockIdx.x * RPB;
  for (int i = tid; i < RPB * K; i += 256) {
    int r = i / K, k = i - r * K;
    int row = row0 + r;
    float v = 0.f;
    if (row < n) v = x[(size_t)row * K + k];
    if (PREB) v += preb[k];
    xs[i] = v;
  }
  __syncthreads();
  const int c = tid % C;
  const int g = tid / C;
  float acc[R];
#pragma unroll
  for (int r = 0; r < R; r++) acc[r] = 0.f;
  const float* xg = xs + g * R * K;
  for (int k = 0; k < K; k += 4) {
    float w0 = W[(k + 0) * C + c];
    float w1 = W[(k + 1) * C + c];
    float w2 = W[(k + 2) * C + c];
    float w3 = W[(k + 3) * C + c];
#pragma unroll
    for (int r = 0; r < R; r++) {
      const float* xp = xg + r * K + k;
      acc[r] += xp[0] * w0;
      acc[r] += xp[1] * w1;
      acc[r] += xp[2] * w2;
      acc[r] += xp[3] * w3;
    }
  }
  float pb = POSTB ? postb[c] : 0.f;
#pragma unroll
  for (int r = 0; r < R; r++) {
    int row = row0 + g * R + r;
    if (row < n) {
      float v = acc[r] + pb;
      if (ACT == 1) v = (v >= 0.f) ? v : 0.01f * v;
      if (ACT == 2) v = (v > 0.f) ? v : 0.f;
      out[(size_t)row * C + c] = v;
    }
  }
}

// per-node inverse l2 norm of x[n,64]
__global__ __launch_bounds__(256) void l2scale_k(const float* __restrict__ x,
                                                 float* __restrict__ s, int n) {
  int node = blockIdx.x * 4 + (threadIdx.x >> 6);
  if (node >= n) return;
  int lane = threadIdx.x & 63;
  float v = x[(size_t)node * 64 + lane];
  float ss = v * v;
#pragma unroll
  for (int o = 32; o > 0; o >>= 1) ss += __shfl_xor(ss, o, 64);
  if (lane == 0) s[node] = 1.0f / fmaxf(sqrtf(ss), 1e-12f);
}

// phase A: per edge cos sim -> v = exp(cos)/TAU; store V; atomicMax into M[src]
__global__ __launch_bounds__(256) void edge_a_k(const int* __restrict__ src,
                                                const int* __restrict__ dst,
                                                const float* __restrict__ xl,
                                                const float* __restrict__ xr,
                                                const float* __restrict__ sl,
                                                const float* __restrict__ sr,
                                                float* __restrict__ V,
                                                float* __restrict__ M, int E) {
  int e = blockIdx.x * 4 + (threadIdx.x >> 6);
  if (e >= E) return;
  int lane = threadIdx.x & 63;
  int s = src[e], d = dst[e];
  float p = xl[(size_t)s * 64 + lane] * xr[(size_t)d * 64 + lane];
#pragma unroll
  for (int o = 32; o > 0; o >>= 1) p += __shfl_xor(p, o, 64);
  if (lane == 0) {
    float cosv = p * sl[s] * sr[d];
    float v = expf(cosv) * 4.0f;  // 1/TAU, TAU=0.25
    V[e] = v;
    atomicMax(reinterpret_cast<int*>(M) + s, __float_as_int(v));  // v>0 always
  }
}

// phase B: den[src] += exp(v - m[src])
__global__ __launch_bounds__(256) void edge_b_k(const int* __restrict__ src,
                                                const float* __restrict__ V,
                                                const float* __restrict__ M,
                                                float* __restrict__ DEN, int E) {
  int e = blockIdx.x * 256 + threadIdx.x;
  if (e >= E) return;
  int s = src[e];
  float ee = expf(V[e] - M[s]);
  unsafeAtomicAdd(&DEN[s], ee);
}

// phase C: AGG[dst] += xl[src] * a,  a = exp(v-m[src])/den[src]
__global__ __launch_bounds__(256) void edge_c_k(const int* __restrict__ src,
                                                const int* __restrict__ dst,
                                                const float* __restrict__ xl,
                                                const float* __restrict__ V,
                                                const float* __restrict__ M,
                                                const float* __restrict__ DEN,
                                                float* __restrict__ AGG, int E) {
  int e = blockIdx.x * 4 + (threadIdx.x >> 6);
  if (e >= E) return;
  int lane = threadIdx.x & 63;
  int s = src[e], d = dst[e];
  float a = 0.f;
  if (lane == 0) a = expf(V[e] - M[s]) / DEN[s];
  a = __shfl(a, 0, 64);
  unsafeAtomicAdd(&AGG[(size_t)d * 64 + lane], xl[(size_t)s * 64 + lane] * a);
}

extern "C" void kernel_launch(void* const* d_in, const int* in_sizes, int n_in,
                              void* d_out, int out_size, void* d_ws, size_t ws_size,
                              hipStream_t stream) {
  const int N = in_sizes[0] / IN_C;
  const int E = in_sizes[1] / 2;
  const int* ei  = (const int*)d_in[1];
  const int* src = ei;
  const int* dst = ei + E;

  float* ws = (float*)d_ws;
  int*   FLAG = (int*)ws;                         // ws[0..3]
  float* XF   = ws + 4;                           // N*128 (x as f32); reused: XL|XR
  float* H0   = XF + (size_t)N * 128;             // N*128; reused: H2
  float* AGG  = H0 + (size_t)N * 128;             // N*64;  reused tail: OUTF
  float* Hb   = AGG + (size_t)N * 64;             // N*64;  reused: T
  float* V    = Hb + (size_t)N * 64;              // E
  float* M    = V + E;                            // N
  float* DEN  = M + N;                            // N
  float* SL   = DEN + N;                          // N
  float* SR   = SL + N;                           // N
  float* WF   = SR + N;                           // ~56K weights as f32

  float* XL = XF;                    // N*64
  float* XR = XF + (size_t)N * 64;   // N*64
  float* OUTF = AGG;                 // N*32, reuse after AGG dead

  dim3 blk(256);
  auto nblk = [](long total, int per) { return dim3((unsigned)((total + per - 1) / per)); };

  // ---- dtype detect + convert everything to f32 ----
  detect_k<<<1, blk, 0, stream>>>((const unsigned short*)d_in[0], FLAG);
  cvt_k<<<nblk((long)N * 128, 256), blk, 0, stream>>>(d_in[0], XF, N * 128, FLAG);
  // weights: inputs 2..15 into WF, track offsets
  float* wp[16];
  {
    float* off = WF;
    for (int i = 2; i < 16; i++) {
      wp[i] = off;
      cvt_k<<<nblk(in_sizes[i], 256), blk, 0, stream>>>(d_in[i], off, in_sizes[i], FLAG);
      off += in_sizes[i];
    }
  }
  const float *W_in = wp[2], *b_in = wp[3], *Wl1 = wp[4], *Wr1 = wp[5],
              *bias1 = wp[6], *Wc1 = wp[7], *Wl2 = wp[8], *Wr2 = wp[9],
              *bias2 = wp[10], *Wc2 = wp[11], *W3 = wp[12], *b3 = wp[13],
              *W4 = wp[14], *b4 = wp[15];

  // h0 = leaky(x @ W_in + b_in)
  lin_k<128, 128, 1, false, true>
      <<<nblk(N, 16), blk, 0, stream>>>(XF, W_in, nullptr, b_in, H0, N);

  auto run_gat = [&](const float* xlp, const float* xrp) {
    hipMemsetAsync(M, 0, sizeof(float) * (size_t)N * 2, stream);      // M, DEN
    hipMemsetAsync(AGG, 0, sizeof(float) * (size_t)N * 64, stream);
    l2scale_k<<<nblk(N, 4), blk, 0, stream>>>(xlp, SL, N);
    l2scale_k<<<nblk(N, 4), blk, 0, stream>>>(xrp, SR, N);
    edge_a_k<<<nblk(E, 4), blk, 0, stream>>>(src, dst, xlp, xrp, SL, SR, V, M, E);
    edge_b_k<<<nblk(E, 256), blk, 0, stream>>>(src, V, M, DEN, E);
    edge_c_k<<<nblk(E, 4), blk, 0, stream>>>(src, dst, xlp, V, M, DEN, AGG, E);
  };

  // ---- GAT layer 1 (XL/XR overwrite XF — consumed by lin above already) ----
  lin_k<128, 64, 0, false, false>
      <<<nblk(N, 32), blk, 0, stream>>>(H0, Wl1, nullptr, nullptr, XL, N);
  lin_k<128, 64, 0, false, false>
      <<<nblk(N, 32), blk, 0, stream>>>(H0, Wr1, nullptr, nullptr, XR, N);
  run_gat(XL, XR);
  // h1 = leaky((agg + bias1) @ Wc1)
  lin_k<64, 64, 1, true, false>
      <<<nblk(N, 32), blk, 0, stream>>>(AGG, Wc1, bias1, nullptr, Hb, N);

  // ---- GAT layer 2 ----
  lin_k<64, 64, 0, false, false>
      <<<nblk(N, 32), blk, 0, stream>>>(Hb, Wl2, nullptr, nullptr, XL, N);
  lin_k<64, 64, 0, false, false>
      <<<nblk(N, 32), blk, 0, stream>>>(Hb, Wr2, nullptr, nullptr, XR, N);
  run_gat(XL, XR);
  float* H2 = H0;  // reuse
  lin_k<64, 64, 1, true, false>
      <<<nblk(N, 32), blk, 0, stream>>>(AGG, Wc2, bias2, nullptr, H2, N);

  // ---- head: z = relu(h @ W3 + b3) @ W4 + b4 ----
  float* T = Hb;  // reuse (Hb dead after XL/XR layer-2 lins)
  lin_k<64, 64, 2, false, true>
      <<<nblk(N, 32), blk, 0, stream>>>(H2, W3, nullptr, b3, T, N);
  lin_k<64, 32, 0, false, true>
      <<<nblk(N, 64), blk, 0, stream>>>(T, W4, nullptr, b4, OUTF, N);  // AGG dead -> OUTF
  out_k<<<nblk((long)N * 32, 256), blk, 0, stream>>>(OUTF, d_out, N * 32, FLAG);
}

// Round 3
// 2009.157 us; speedup vs baseline: 1.2867x; 1.2867x over previous
//
#include <hip/hip_runtime.h>
#include <hip/hip_bf16.h>

typedef __hip_bfloat16 bf16;

#define IN_C 128

// ---- dtype detection: flag=1 if buffer is bf16, 0 if float32 ----
__global__ __launch_bounds__(256) void detect_k(const unsigned short* __restrict__ xb,
                                                int* __restrict__ flag) {
  __shared__ int s_sane;
  if (threadIdx.x == 0) s_sane = 0;
  __syncthreads();
  int sane = 0;
  for (int i = threadIdx.x; i < 4096; i += 256) {
    unsigned short h = xb[2 * i];
    int e = (h >> 7) & 0xFF;
    if (e >= 100 && e <= 150) sane++;
  }
  atomicAdd(&s_sane, sane);
  __syncthreads();
  if (threadIdx.x == 0) *flag = (s_sane > 3072) ? 1 : 0;
}

__global__ __launch_bounds__(256) void cvt_k(const void* __restrict__ in,
                                             float* __restrict__ out, int n,
                                             const int* __restrict__ flag) {
  int i = blockIdx.x * 256 + threadIdx.x;
  if (i >= n) return;
  if (*flag) out[i] = __bfloat162float(((const bf16*)in)[i]);
  else       out[i] = ((const float*)in)[i];
}

struct WArgs { const void* p[14]; int off[15]; };
__global__ __launch_bounds__(256) void cvtw_k(WArgs a, float* __restrict__ out,
                                              const int* __restrict__ flag, int total) {
  int i = blockIdx.x * 256 + threadIdx.x;
  if (i >= total) return;
  int s = 0;
#pragma unroll
  for (int j = 1; j < 14; j++) if (i >= a.off[j]) s = j;
  int loc = i - a.off[s];
  if (*flag) out[i] = __bfloat162float(((const bf16*)a.p[s])[loc]);
  else       out[i] = ((const float*)a.p[s])[loc];
}

__global__ __launch_bounds__(256) void out_k(const float* __restrict__ src,
                                             void* __restrict__ out, int n,
                                             const int* __restrict__ flag) {
  int i = blockIdx.x * 256 + threadIdx.x;
  if (i >= n) return;
  float v = src[i];
  if (*flag) ((bf16*)out)[i] = __float2bfloat16(v);
  else       ((float*)out)[i] = v;
}

// out[n,C] = act((x[n,K]+preb) @ W[K,C] + postb)
// ACT: 0 none, 1 leaky(0.01), 2 relu.  NRM: 0 none, 1 out=normalized, 2 out=raw & out2=normalized (C==64 only)
template <int K, int C, int ACT, bool PREB, bool POSTB, int NRM>
__global__ __launch_bounds__(256) void lin_k(const float* __restrict__ x,
                                             const float* __restrict__ W,
                                             const float* __restrict__ preb,
                                             const float* __restrict__ postb,
                                             float* __restrict__ out,
                                             float* __restrict__ out2, int n) {
  constexpr int G = 256 / C;
  constexpr int R = 8;
  constexpr int RPB = G * R;
  __shared__ float xs[RPB * K];
  const int tid = threadIdx.x;
  const int row0 = blockIdx.x * RPB;
  for (int i = tid; i < RPB * K; i += 256) {
    int r = i / K, k = i - r * K;
    int row = row0 + r;
    float v = 0.f;
    if (row < n) v = x[(size_t)row * K + k];
    if (PREB) v += preb[k];
    xs[i] = v;
  }
  __syncthreads();
  const int c = tid % C;
  const int g = tid / C;
  float acc[R];
#pragma unroll
  for (int r = 0; r < R; r++) acc[r] = 0.f;
  const float* xg = xs + g * R * K;
  for (int k = 0; k < K; k += 4) {
    float w0 = W[(k + 0) * C + c];
    float w1 = W[(k + 1) * C + c];
    float w2 = W[(k + 2) * C + c];
    float w3 = W[(k + 3) * C + c];
#pragma unroll
    for (int r = 0; r < R; r++) {
      const float* xp = xg + r * K + k;
      acc[r] += xp[0] * w0;
      acc[r] += xp[1] * w1;
      acc[r] += xp[2] * w2;
      acc[r] += xp[3] * w3;
    }
  }
  float pb = POSTB ? postb[c] : 0.f;
#pragma unroll
  for (int r = 0; r < R; r++) {
    float v = acc[r] + pb;
    if (ACT == 1) v = (v >= 0.f) ? v : 0.01f * v;
    if (ACT == 2) v = (v > 0.f) ? v : 0.f;
    float vn = 0.f;
    if (NRM) {  // C==64: one wave holds the full row -> shfl reduce sumsq
      float ss = v * v;
#pragma unroll
      for (int o = 32; o > 0; o >>= 1) ss += __shfl_xor(ss, o);
      vn = v / fmaxf(sqrtf(ss), 1e-12f);
    }
    int row = row0 + g * R + r;
    if (row < n) {
      if (NRM == 1)      out[(size_t)row * C + c] = vn;
      else               out[(size_t)row * C + c] = v;
      if (NRM == 2)      out2[(size_t)row * C + c] = vn;
    }
  }
}

// ---- CSR build ----
__global__ __launch_bounds__(256) void count_k(const int* __restrict__ src,
                                               const int* __restrict__ dst,
                                               int* __restrict__ cnt_s,
                                               int* __restrict__ cnt_d, int E) {
  int e = blockIdx.x * 256 + threadIdx.x;
  if (e >= E) return;
  atomicAdd(&cnt_s[src[e]], 1);
  atomicAdd(&cnt_d[dst[e]], 1);
}

__global__ __launch_bounds__(1024) void scan2_k(const int* __restrict__ cnt_s,
                                                const int* __restrict__ cnt_d,
                                                int* __restrict__ off_s, int* __restrict__ off_d,
                                                int* __restrict__ cur_s, int* __restrict__ cur_d,
                                                int n) {
  __shared__ int part[1024];
  const int chunk = (n + 1023) / 1024;
  for (int pass = 0; pass < 2; ++pass) {
    const int* cnt = pass ? cnt_d : cnt_s;
    int* off = pass ? off_d : off_s;
    int* cur = pass ? cur_d : cur_s;
    int lo = threadIdx.x * chunk, hi = min(lo + chunk, n);
    int s = 0;
    for (int i = lo; i < hi; i++) s += cnt[i];
    part[threadIdx.x] = s;
    __syncthreads();
    if (threadIdx.x == 0) {
      int r = 0;
      for (int i = 0; i < 1024; i++) { int t = part[i]; part[i] = r; r += t; }
      off[n] = r;
    }
    __syncthreads();
    int run = part[threadIdx.x];
    for (int i = lo; i < hi; i++) { int t = cnt[i]; off[i] = run; cur[i] = run; run += t; }
    __syncthreads();
  }
}

__global__ __launch_bounds__(256) void fill_k(const int* __restrict__ src,
                                              const int* __restrict__ dst,
                                              int* __restrict__ cur_s, int* __restrict__ cur_d,
                                              int* __restrict__ sl_d, int* __restrict__ sl_dpos,
                                              int* __restrict__ dl_src, int E) {
  int e = blockIdx.x * 256 + threadIdx.x;
  if (e >= E) return;
  int s = src[e], d = dst[e];
  int ps = atomicAdd(&cur_s[s], 1);
  int pd = atomicAdd(&cur_d[d], 1);
  sl_d[ps] = d;
  sl_dpos[ps] = pd;
  dl_src[pd] = s;
}

// ---- Phase S: per src node, fused cos/exp/softmax; writes a into dst-order ----
__global__ __launch_bounds__(256) void gat_src_k(const float* __restrict__ XLN,
                                                 const float* __restrict__ XRN,
                                                 const int* __restrict__ off_s,
                                                 const int* __restrict__ sl_d,
                                                 const int* __restrict__ sl_dpos,
                                                 float* __restrict__ A_perm, int n) {
  __shared__ float vbuf[4][256];
  int wv = threadIdx.x >> 6, lane = threadIdx.x & 63;
  int node = blockIdx.x * 4 + wv;
  if (node >= n) return;
  int q = lane >> 4, ql = lane & 15;
  int beg = off_s[node];
  int deg = off_s[node + 1] - beg;
  if (deg <= 0) return;
  int degc = min(deg, 256);
  float4 xl = *(const float4*)&XLN[(size_t)node * 64 + ql * 4];
  for (int i0 = 0; i0 < degc; i0 += 4) {
    int i = i0 + q;
    if (i < degc) {
      int d = sl_d[beg + i];
      float4 xr = *(const float4*)&XRN[(size_t)d * 64 + ql * 4];
      float p = xl.x * xr.x + xl.y * xr.y + xl.z * xr.z + xl.w * xr.w;
      p += __shfl_xor(p, 1); p += __shfl_xor(p, 2);
      p += __shfl_xor(p, 4); p += __shfl_xor(p, 8);
      if (ql == 0) vbuf[wv][i] = expf(p) * 4.0f;  // v = exp(cos)/TAU
    }
  }
  float m = -1e30f;
  for (int i = lane; i < degc; i += 64) m = fmaxf(m, vbuf[wv][i]);
#pragma unroll
  for (int o = 32; o > 0; o >>= 1) m = fmaxf(m, __shfl_xor(m, o));
  float den = 0.f;
  for (int i = lane; i < degc; i += 64) den += expf(vbuf[wv][i] - m);
#pragma unroll
  for (int o = 32; o > 0; o >>= 1) den += __shfl_xor(den, o);
  float inv = 1.0f / den;
  for (int i = lane; i < degc; i += 64) {
    float a = expf(vbuf[wv][i] - m) * inv;
    A_perm[sl_dpos[beg + i]] = a;
  }
}

// ---- Phase D: per dst node, gather xl[src]*a, register-accumulate, one write ----
__global__ __launch_bounds__(256) void gat_dst_k(const float* __restrict__ XL,
                                                 const float* __restrict__ A_perm,
                                                 const int* __restrict__ off_d,
                                                 const int* __restrict__ dl_src,
                                                 float* __restrict__ AGG, int n) {
  int wv = threadIdx.x >> 6, lane = threadIdx.x & 63;
  int node = blockIdx.x * 4 + wv;
  if (node >= n) return;
  int q = lane >> 4, ql = lane & 15;
  int beg = off_d[node];
  int deg = off_d[node + 1] - beg;
  float4 acc = {0.f, 0.f, 0.f, 0.f};
  for (int i0 = 0; i0 < deg; i0 += 4) {
    int i = i0 + q;
    if (i < deg) {
      int s = dl_src[beg + i];
      float a = A_perm[beg + i];
      float4 xv = *(const float4*)&XL[(size_t)s * 64 + ql * 4];
      acc.x += a * xv.x; acc.y += a * xv.y; acc.z += a * xv.z; acc.w += a * xv.w;
    }
  }
  acc.x += __shfl_xor(acc.x, 16); acc.y += __shfl_xor(acc.y, 16);
  acc.z += __shfl_xor(acc.z, 16); acc.w += __shfl_xor(acc.w, 16);
  acc.x += __shfl_xor(acc.x, 32); acc.y += __shfl_xor(acc.y, 32);
  acc.z += __shfl_xor(acc.z, 32); acc.w += __shfl_xor(acc.w, 32);
  if (q == 0) *(float4*)&AGG[(size_t)node * 64 + ql * 4] = acc;
}

extern "C" void kernel_launch(void* const* d_in, const int* in_sizes, int n_in,
                              void* d_out, int out_size, void* d_ws, size_t ws_size,
                              hipStream_t stream) {
  const int N = in_sizes[0] / IN_C;
  const int E = in_sizes[1] / 2;
  const int* ei  = (const int*)d_in[1];
  const int* src = ei;
  const int* dst = ei + E;

  // ---- workspace layout (floats/ints, 4B units) ----
  char* wsb = (char*)d_ws;
  size_t o = 0;
  auto alloc = [&](size_t elems) { void* p = wsb + o; o += elems * 4; return p; };
  int*   FLAG   = (int*)alloc(16);
  float* WF     = (float*)alloc(60000);
  int*   CNT_S  = (int*)alloc(N);
  int*   CNT_D  = (int*)alloc(N);
  int*   OFF_S  = (int*)alloc(N + 1);
  int*   OFF_D  = (int*)alloc(N + 1);
  int*   CUR_S  = (int*)alloc(N);
  int*   CUR_D  = (int*)alloc(N);
  int*   SL_D   = (int*)alloc(E);
  int*   SL_DP  = (int*)alloc(E);
  int*   DL_SRC = (int*)alloc(E);
  float* A_PERM = (float*)alloc(E);
  float* bufA   = (float*)alloc((size_t)N * 128);  // XF -> XLN | XRN
  float* bufB   = (float*)alloc((size_t)N * 128);  // H0 -> AGG1/Hb | AGG2/H2
  float* bufC   = (float*)alloc((size_t)N * 64);   // XL

  float* XF  = bufA;
  float* XLN = bufA;
  float* XRN = bufA + (size_t)N * 64;
  float* H0  = bufB;
  float* B1  = bufB;                    // AGG1 / Hb / T
  float* B2  = bufB + (size_t)N * 64;   // AGG2 / H2
  float* XL  = bufC;

  dim3 blk(256);
  auto nblk = [](long total, int per) { return dim3((unsigned)((total + per - 1) / per)); };

  // ---- dtype detect + convert ----
  detect_k<<<1, blk, 0, stream>>>((const unsigned short*)d_in[0], FLAG);
  cvt_k<<<nblk((long)N * 128, 256), blk, 0, stream>>>(d_in[0], XF, N * 128, FLAG);
  WArgs wa;
  int wtot = 0;
  float* wp[16];
  for (int i = 2; i < 16; i++) {
    wa.p[i - 2] = d_in[i];
    wa.off[i - 2] = wtot;
    wp[i] = WF + wtot;
    wtot += in_sizes[i];
  }
  wa.off[14] = wtot;
  cvtw_k<<<nblk(wtot, 256), blk, 0, stream>>>(wa, WF, FLAG, wtot);
  const float *W_in = wp[2], *b_in = wp[3], *Wl1 = wp[4], *Wr1 = wp[5],
              *bias1 = wp[6], *Wc1 = wp[7], *Wl2 = wp[8], *Wr2 = wp[9],
              *bias2 = wp[10], *Wc2 = wp[11], *W3 = wp[12], *b3 = wp[13],
              *W4 = wp[14], *b4 = wp[15];

  // ---- CSR build (once; both GAT layers share the graph) ----
  hipMemsetAsync(CNT_S, 0, sizeof(int) * (size_t)N * 2, stream);  // CNT_S, CNT_D contiguous
  count_k<<<nblk(E, 256), blk, 0, stream>>>(src, dst, CNT_S, CNT_D, E);
  scan2_k<<<1, dim3(1024), 0, stream>>>(CNT_S, CNT_D, OFF_S, OFF_D, CUR_S, CUR_D, N);
  fill_k<<<nblk(E, 256), blk, 0, stream>>>(src, dst, CUR_S, CUR_D, SL_D, SL_DP, DL_SRC, E);

  // h0 = leaky(x @ W_in + b_in)   (reads bufA, writes bufB)
  lin_k<128, 128, 1, false, true, 0>
      <<<nblk(N, 16), blk, 0, stream>>>(XF, W_in, nullptr, b_in, H0, nullptr, N);

  // ---- GAT layer 1 ----
  lin_k<128, 64, 0, false, false, 2>   // XL(raw)->bufC, XLN->A1
      <<<nblk(N, 32), blk, 0, stream>>>(H0, Wl1, nullptr, nullptr, XL, XLN, N);
  lin_k<128, 64, 0, false, false, 1>   // XRN->A2
      <<<nblk(N, 32), blk, 0, stream>>>(H0, Wr1, nullptr, nullptr, XRN, nullptr, N);
  gat_src_k<<<nblk(N, 4), blk, 0, stream>>>(XLN, XRN, OFF_S, SL_D, SL_DP, A_PERM, N);
  gat_dst_k<<<nblk(N, 4), blk, 0, stream>>>(XL, A_PERM, OFF_D, DL_SRC, B1, N);  // AGG1 (H0 dead)
  lin_k<64, 64, 1, true, false, 0>     // Hb = leaky((AGG1+bias1)@Wc1), in-place B1
      <<<nblk(N, 32), blk, 0, stream>>>(B1, Wc1, bias1, nullptr, B1, nullptr, N);

  // ---- GAT layer 2 ----
  lin_k<64, 64, 0, false, false, 2>    // XL2->bufC, XLN2->A1
      <<<nblk(N, 32), blk, 0, stream>>>(B1, Wl2, nullptr, nullptr, XL, XLN, N);
  lin_k<64, 64, 0, false, false, 1>    // XRN2->A2
      <<<nblk(N, 32), blk, 0, stream>>>(B1, Wr2, nullptr, nullptr, XRN, nullptr, N);
  gat_src_k<<<nblk(N, 4), blk, 0, stream>>>(XLN, XRN, OFF_S, SL_D, SL_DP, A_PERM, N);
  gat_dst_k<<<nblk(N, 4), blk, 0, stream>>>(XL, A_PERM, OFF_D, DL_SRC, B2, N);  // AGG2
  lin_k<64, 64, 1, true, false, 0>     // H2 = leaky((AGG2+bias2)@Wc2), in-place B2
      <<<nblk(N, 32), blk, 0, stream>>>(B2, Wc2, bias2, nullptr, B2, nullptr, N);

  // ---- head ----
  lin_k<64, 64, 2, false, true, 0>     // T = relu(H2@W3+b3) -> B1 (Hb dead)
      <<<nblk(N, 32), blk, 0, stream>>>(B2, W3, nullptr, b3, B1, nullptr, N);
  lin_k<64, 32, 0, false, true, 0>     // OUT = T@W4+b4 -> A1 (XLN dead)
      <<<nblk(N, 64), blk, 0, stream>>>(B1, W4, nullptr, b4, bufA, nullptr, N);
  out_k<<<nblk((long)N * 32, 256), blk, 0, stream>>>(bufA, d_out, N * 32, FLAG);
}

// Round 4
// 1546.185 us; speedup vs baseline: 1.6720x; 1.2994x over previous
//
#include <hip/hip_runtime.h>
#include <hip/hip_bf16.h>

typedef __hip_bfloat16 bf16;

#define IN_C 128

// ---- dtype detection: flag=1 if buffer is bf16, 0 if float32 ----
__global__ __launch_bounds__(256) void detect_k(const unsigned short* __restrict__ xb,
                                                int* __restrict__ flag) {
  __shared__ int s_sane;
  if (threadIdx.x == 0) s_sane = 0;
  __syncthreads();
  int sane = 0;
  for (int i = threadIdx.x; i < 4096; i += 256) {
    unsigned short h = xb[2 * i];
    int e = (h >> 7) & 0xFF;
    if (e >= 100 && e <= 150) sane++;
  }
  atomicAdd(&s_sane, sane);
  __syncthreads();
  if (threadIdx.x == 0) *flag = (s_sane > 3072) ? 1 : 0;
}

__global__ __launch_bounds__(256) void cvt_k(const void* __restrict__ in,
                                             float* __restrict__ out, int n,
                                             const int* __restrict__ flag) {
  int i = blockIdx.x * 256 + threadIdx.x;
  if (i >= n) return;
  if (*flag) out[i] = __bfloat162float(((const bf16*)in)[i]);
  else       out[i] = ((const float*)in)[i];
}

struct WArgs { const void* p[14]; int off[15]; };
__global__ __launch_bounds__(256) void cvtw_k(WArgs a, float* __restrict__ out,
                                              const int* __restrict__ flag, int total) {
  int i = blockIdx.x * 256 + threadIdx.x;
  if (i >= total) return;
  int s = 0;
#pragma unroll
  for (int j = 1; j < 14; j++) if (i >= a.off[j]) s = j;
  int loc = i - a.off[s];
  if (*flag) out[i] = __bfloat162float(((const bf16*)a.p[s])[loc]);
  else       out[i] = ((const float*)a.p[s])[loc];
}

__global__ __launch_bounds__(256) void out_k(const float* __restrict__ src,
                                             void* __restrict__ out, int n,
                                             const int* __restrict__ flag) {
  int i = blockIdx.x * 256 + threadIdx.x;
  if (i >= n) return;
  float v = src[i];
  if (*flag) ((bf16*)out)[i] = __float2bfloat16(v);
  else       ((float*)out)[i] = v;
}

// out[n,C] = act((x[n,K]+preb) @ W[K,C] + postb)
// ACT: 0 none, 1 leaky(0.01), 2 relu.  NRM: 0 none, 1 out=normalized, 2 out=raw & out2=normalized (C==64 only)
template <int K, int C, int ACT, bool PREB, bool POSTB, int NRM>
__global__ __launch_bounds__(256) void lin_k(const float* __restrict__ x,
                                             const float* __restrict__ W,
                                             const float* __restrict__ preb,
                                             const float* __restrict__ postb,
                                             float* __restrict__ out,
                                             float* __restrict__ out2, int n) {
  constexpr int G = 256 / C;
  constexpr int R = 8;
  constexpr int RPB = G * R;
  __shared__ float xs[RPB * K];
  const int tid = threadIdx.x;
  const int row0 = blockIdx.x * RPB;
  for (int i = tid; i < RPB * K; i += 256) {
    int r = i / K, k = i - r * K;
    int row = row0 + r;
    float v = 0.f;
    if (row < n) v = x[(size_t)row * K + k];
    if (PREB) v += preb[k];
    xs[i] = v;
  }
  __syncthreads();
  const int c = tid % C;
  const int g = tid / C;
  float acc[R];
#pragma unroll
  for (int r = 0; r < R; r++) acc[r] = 0.f;
  const float* xg = xs + g * R * K;
  for (int k = 0; k < K; k += 4) {
    float w0 = W[(k + 0) * C + c];
    float w1 = W[(k + 1) * C + c];
    float w2 = W[(k + 2) * C + c];
    float w3 = W[(k + 3) * C + c];
#pragma unroll
    for (int r = 0; r < R; r++) {
      const float* xp = xg + r * K + k;
      acc[r] += xp[0] * w0;
      acc[r] += xp[1] * w1;
      acc[r] += xp[2] * w2;
      acc[r] += xp[3] * w3;
    }
  }
  float pb = POSTB ? postb[c] : 0.f;
#pragma unroll
  for (int r = 0; r < R; r++) {
    float v = acc[r] + pb;
    if (ACT == 1) v = (v >= 0.f) ? v : 0.01f * v;
    if (ACT == 2) v = (v > 0.f) ? v : 0.f;
    float vn = 0.f;
    if (NRM) {  // C==64: one wave holds the full row -> shfl reduce sumsq
      float ss = v * v;
#pragma unroll
      for (int o = 32; o > 0; o >>= 1) ss += __shfl_xor(ss, o);
      vn = v / fmaxf(sqrtf(ss), 1e-12f);
    }
    int row = row0 + g * R + r;
    if (row < n) {
      if (NRM == 1)      out[(size_t)row * C + c] = vn;
      else               out[(size_t)row * C + c] = v;
      if (NRM == 2)      out2[(size_t)row * C + c] = vn;
    }
  }
}

// ---- CSR build ----
__global__ __launch_bounds__(256) void count_k(const int* __restrict__ src,
                                               const int* __restrict__ dst,
                                               int* __restrict__ cnt_s,
                                               int* __restrict__ cnt_d, int E) {
  int e = blockIdx.x * 256 + threadIdx.x;
  if (e >= E) return;
  atomicAdd(&cnt_s[src[e]], 1);
  atomicAdd(&cnt_d[dst[e]], 1);
}

// hierarchical exclusive scan, 2048 elems/block, gridDim.y selects {src,dst}
__global__ __launch_bounds__(256) void scan_local_k(const int* __restrict__ cnt_s,
                                                    const int* __restrict__ cnt_d,
                                                    int* __restrict__ off_s,
                                                    int* __restrict__ off_d,
                                                    int* __restrict__ part, int nb, int n) {
  const int* cnt = blockIdx.y ? cnt_d : cnt_s;
  int* off = blockIdx.y ? off_d : off_s;
  __shared__ int sd[256];
  int t = threadIdx.x;
  int base = blockIdx.x * 2048 + t * 8;
  int v[8], s = 0;
#pragma unroll
  for (int j = 0; j < 8; j++) {
    int idx = base + j;
    v[j] = (idx < n) ? cnt[idx] : 0;
    s += v[j];
  }
  sd[t] = s;
  __syncthreads();
  for (int o = 1; o < 256; o <<= 1) {
    int x = (t >= o) ? sd[t - o] : 0;
    __syncthreads();
    sd[t] += x;
    __syncthreads();
  }
  int excl = sd[t] - s;
  if (t == 255) part[blockIdx.y * nb + blockIdx.x] = sd[255];
  int run = excl;
#pragma unroll
  for (int j = 0; j < 8; j++) {
    int idx = base + j;
    if (idx < n) off[idx] = run;
    run += v[j];
  }
}

__global__ __launch_bounds__(256) void scan_add_k(int* __restrict__ off_s,
                                                  int* __restrict__ off_d,
                                                  int* __restrict__ cur_s,
                                                  int* __restrict__ cur_d,
                                                  const int* __restrict__ part,
                                                  int nb, int n) {
  int* off = blockIdx.y ? off_d : off_s;
  int* cur = blockIdx.y ? cur_d : cur_s;
  const int* p = part + blockIdx.y * nb;
  __shared__ int s_pref;
  if (threadIdx.x == 0) {
    int s = 0;
    for (int i = 0; i < (int)blockIdx.x; i++) s += p[i];
    s_pref = s;
    if (blockIdx.x == 0) {
      int tot = 0;
      for (int i = 0; i < nb; i++) tot += p[i];
      off[n] = tot;
    }
  }
  __syncthreads();
  int pref = s_pref;
  int base = blockIdx.x * 2048 + threadIdx.x * 8;
#pragma unroll
  for (int j = 0; j < 8; j++) {
    int idx = base + j;
    if (idx < n) { int val = off[idx] + pref; off[idx] = val; cur[idx] = val; }
  }
}

__global__ __launch_bounds__(256) void fill_k(const int* __restrict__ src,
                                              const int* __restrict__ dst,
                                              int* __restrict__ cur_s, int* __restrict__ cur_d,
                                              int* __restrict__ sl_d, int* __restrict__ sl_dpos,
                                              int* __restrict__ dl_src, int E) {
  int e = blockIdx.x * 256 + threadIdx.x;
  if (e >= E) return;
  int s = src[e], d = dst[e];
  int ps = atomicAdd(&cur_s[s], 1);
  int pd = atomicAdd(&cur_d[d], 1);
  sl_d[ps] = d;
  sl_dpos[ps] = pd;
  dl_src[pd] = s;
}

// ---- Phase S: per src node, fused cos/exp/softmax; writes a into dst-order ----
__global__ __launch_bounds__(256) void gat_src_k(const float* __restrict__ XLN,
                                                 const float* __restrict__ XRN,
                                                 const int* __restrict__ off_s,
                                                 const int* __restrict__ sl_d,
                                                 const int* __restrict__ sl_dpos,
                                                 float* __restrict__ A_perm, int n) {
  __shared__ float vbuf[4][256];
  int wv = threadIdx.x >> 6, lane = threadIdx.x & 63;
  int node = blockIdx.x * 4 + wv;
  if (node >= n) return;
  int q = lane >> 4, ql = lane & 15;
  int beg = off_s[node];
  int deg = off_s[node + 1] - beg;
  if (deg <= 0) return;
  int degc = min(deg, 256);
  float4 xl = *(const float4*)&XLN[(size_t)node * 64 + ql * 4];
  for (int i0 = 0; i0 < degc; i0 += 4) {
    int i = i0 + q;
    if (i < degc) {
      int d = sl_d[beg + i];
      float4 xr = *(const float4*)&XRN[(size_t)d * 64 + ql * 4];
      float p = xl.x * xr.x + xl.y * xr.y + xl.z * xr.z + xl.w * xr.w;
      p += __shfl_xor(p, 1); p += __shfl_xor(p, 2);
      p += __shfl_xor(p, 4); p += __shfl_xor(p, 8);
      if (ql == 0) vbuf[wv][i] = expf(p) * 4.0f;  // v = exp(cos)/TAU
    }
  }
  float m = -1e30f;
  for (int i = lane; i < degc; i += 64) m = fmaxf(m, vbuf[wv][i]);
#pragma unroll
  for (int o = 32; o > 0; o >>= 1) m = fmaxf(m, __shfl_xor(m, o));
  float den = 0.f;
  for (int i = lane; i < degc; i += 64) den += expf(vbuf[wv][i] - m);
#pragma unroll
  for (int o = 32; o > 0; o >>= 1) den += __shfl_xor(den, o);
  float inv = 1.0f / den;
  for (int i = lane; i < degc; i += 64) {
    float a = expf(vbuf[wv][i] - m) * inv;
    A_perm[sl_dpos[beg + i]] = a;
  }
}

// ---- Phase D: per dst node, gather xl[src]*a, register-accumulate, one write ----
__global__ __launch_bounds__(256) void gat_dst_k(const float* __restrict__ XL,
                                                 const float* __restrict__ A_perm,
                                                 const int* __restrict__ off_d,
                                                 const int* __restrict__ dl_src,
                                                 float* __restrict__ AGG, int n) {
  int wv = threadIdx.x >> 6, lane = threadIdx.x & 63;
  int node = blockIdx.x * 4 + wv;
  if (node >= n) return;
  int q = lane >> 4, ql = lane & 15;
  int beg = off_d[node];
  int deg = off_d[node + 1] - beg;
  float4 acc = {0.f, 0.f, 0.f, 0.f};
  for (int i0 = 0; i0 < deg; i0 += 4) {
    int i = i0 + q;
    if (i < deg) {
      int s = dl_src[beg + i];
      float a = A_perm[beg + i];
      float4 xv = *(const float4*)&XL[(size_t)s * 64 + ql * 4];
      acc.x += a * xv.x; acc.y += a * xv.y; acc.z += a * xv.z; acc.w += a * xv.w;
    }
  }
  acc.x += __shfl_xor(acc.x, 16); acc.y += __shfl_xor(acc.y, 16);
  acc.z += __shfl_xor(acc.z, 16); acc.w += __shfl_xor(acc.w, 16);
  acc.x += __shfl_xor(acc.x, 32); acc.y += __shfl_xor(acc.y, 32);
  acc.z += __shfl_xor(acc.z, 32); acc.w += __shfl_xor(acc.w, 32);
  if (q == 0) *(float4*)&AGG[(size_t)node * 64 + ql * 4] = acc;
}

extern "C" void kernel_launch(void* const* d_in, const int* in_sizes, int n_in,
                              void* d_out, int out_size, void* d_ws, size_t ws_size,
                              hipStream_t stream) {
  const int N = in_sizes[0] / IN_C;
  const int E = in_sizes[1] / 2;
  const int* ei  = (const int*)d_in[1];
  const int* src = ei;
  const int* dst = ei + E;

  // ---- workspace layout ----
  char* wsb = (char*)d_ws;
  size_t o = 0;
  auto alloc = [&](size_t elems) { void* p = wsb + o; o += elems * 4; return p; };
  int*   FLAG   = (int*)alloc(16);
  float* WF     = (float*)alloc(60000);
  int*   CNT_S  = (int*)alloc(N);
  int*   CNT_D  = (int*)alloc(N);
  int*   OFF_S  = (int*)alloc(N + 1);
  int*   OFF_D  = (int*)alloc(N + 1);
  int*   CUR_S  = (int*)alloc(N);
  int*   CUR_D  = (int*)alloc(N);
  int*   PART   = (int*)alloc(256);
  int*   SL_D   = (int*)alloc(E);
  int*   SL_DP  = (int*)alloc(E);
  int*   DL_SRC = (int*)alloc(E);
  float* A_PERM = (float*)alloc(E);
  float* bufA   = (float*)alloc((size_t)N * 128);  // XF -> XLN | XRN
  float* bufB   = (float*)alloc((size_t)N * 128);  // H0 -> AGG1/Hb | AGG2/H2
  float* bufC   = (float*)alloc((size_t)N * 64);   // XL

  float* XF  = bufA;
  float* XLN = bufA;
  float* XRN = bufA + (size_t)N * 64;
  float* H0  = bufB;
  float* B1  = bufB;                    // AGG1 / Hb / T
  float* B2  = bufB + (size_t)N * 64;   // AGG2 / H2
  float* XL  = bufC;

  dim3 blk(256);
  auto nblk = [](long total, int per) { return dim3((unsigned)((total + per - 1) / per)); };

  // ---- dtype detect + convert ----
  detect_k<<<1, blk, 0, stream>>>((const unsigned short*)d_in[0], FLAG);
  cvt_k<<<nblk((long)N * 128, 256), blk, 0, stream>>>(d_in[0], XF, N * 128, FLAG);
  WArgs wa;
  int wtot = 0;
  float* wp[16];
  for (int i = 2; i < 16; i++) {
    wa.p[i - 2] = d_in[i];
    wa.off[i - 2] = wtot;
    wp[i] = WF + wtot;
    wtot += in_sizes[i];
  }
  wa.off[14] = wtot;
  cvtw_k<<<nblk(wtot, 256), blk, 0, stream>>>(wa, WF, FLAG, wtot);
  const float *W_in = wp[2], *b_in = wp[3], *Wl1 = wp[4], *Wr1 = wp[5],
              *bias1 = wp[6], *Wc1 = wp[7], *Wl2 = wp[8], *Wr2 = wp[9],
              *bias2 = wp[10], *Wc2 = wp[11], *W3 = wp[12], *b3 = wp[13],
              *W4 = wp[14], *b4 = wp[15];

  // ---- CSR build (once; both GAT layers share the graph) ----
  hipMemsetAsync(CNT_S, 0, sizeof(int) * (size_t)N * 2, stream);  // CNT_S, CNT_D contiguous
  count_k<<<nblk(E, 256), blk, 0, stream>>>(src, dst, CNT_S, CNT_D, E);
  {
    int nb = (N + 2047) / 2048;
    dim3 g(nb, 2);
    scan_local_k<<<g, blk, 0, stream>>>(CNT_S, CNT_D, OFF_S, OFF_D, PART, nb, N);
    scan_add_k<<<g, blk, 0, stream>>>(OFF_S, OFF_D, CUR_S, CUR_D, PART, nb, N);
  }
  fill_k<<<nblk(E, 256), blk, 0, stream>>>(src, dst, CUR_S, CUR_D, SL_D, SL_DP, DL_SRC, E);

  // h0 = leaky(x @ W_in + b_in)
  lin_k<128, 128, 1, false, true, 0>
      <<<nblk(N, 16), blk, 0, stream>>>(XF, W_in, nullptr, b_in, H0, nullptr, N);

  // ---- GAT layer 1 ----
  lin_k<128, 64, 0, false, false, 2>   // XL(raw)->bufC, XLN->A1
      <<<nblk(N, 32), blk, 0, stream>>>(H0, Wl1, nullptr, nullptr, XL, XLN, N);
  lin_k<128, 64, 0, false, false, 1>   // XRN->A2
      <<<nblk(N, 32), blk, 0, stream>>>(H0, Wr1, nullptr, nullptr, XRN, nullptr, N);
  gat_src_k<<<nblk(N, 4), blk, 0, stream>>>(XLN, XRN, OFF_S, SL_D, SL_DP, A_PERM, N);
  gat_dst_k<<<nblk(N, 4), blk, 0, stream>>>(XL, A_PERM, OFF_D, DL_SRC, B1, N);
  lin_k<64, 64, 1, true, false, 0>
      <<<nblk(N, 32), blk, 0, stream>>>(B1, Wc1, bias1, nullptr, B1, nullptr, N);

  // ---- GAT layer 2 ----
  lin_k<64, 64, 0, false, false, 2>
      <<<nblk(N, 32), blk, 0, stream>>>(B1, Wl2, nullptr, nullptr, XL, XLN, N);
  lin_k<64, 64, 0, false, false, 1>
      <<<nblk(N, 32), blk, 0, stream>>>(B1, Wr2, nullptr, nullptr, XRN, nullptr, N);
  gat_src_k<<<nblk(N, 4), blk, 0, stream>>>(XLN, XRN, OFF_S, SL_D, SL_DP, A_PERM, N);
  gat_dst_k<<<nblk(N, 4), blk, 0, stream>>>(XL, A_PERM, OFF_D, DL_SRC, B2, N);
  lin_k<64, 64, 1, true, false, 0>
      <<<nblk(N, 32), blk, 0, stream>>>(B2, Wc2, bias2, nullptr, B2, nullptr, N);

  // ---- head ----
  lin_k<64, 64, 2, false, true, 0>
      <<<nblk(N, 32), blk, 0, stream>>>(B2, W3, nullptr, b3, B1, nullptr, N);
  lin_k<64, 32, 0, false, true, 0>
      <<<nblk(N, 64), blk, 0, stream>>>(B1, W4, nullptr, b4, bufA, nullptr, N);
  out_k<<<nblk((long)N * 32, 256), blk, 0, stream>>>(bufA, d_out, N * 32, FLAG);
}